// Round 6
// baseline (173.253 us; speedup 1.0000x reference)
//
#include <hip/hip_runtime.h>

#define NB   512   // batch
#define IND  128   // input dim
#define H    512   // hidden
#define OUTD 25    // out dim

__device__ __forceinline__ float silu_f(float v) {
    return v / (1.0f + __expf(-v));
}

__device__ __forceinline__ float dot4(float4 a, float4 b) {
    return fmaf(a.x, b.x, fmaf(a.y, b.y, fmaf(a.z, b.z, a.w * b.w)));
}

// ---------------------------------------------------------------------------
// K1: h = silu(x @ W_in^T + b_in)   (512x512, K=128)
// 128 blocks, 256 threads; each block does 4 batch rows, each thread 2 cols.
// ---------------------------------------------------------------------------
__global__ __launch_bounds__(256) void k_hin(const float* __restrict__ x,
                                             const float* __restrict__ Win,
                                             const float* __restrict__ bin,
                                             float* __restrict__ h) {
    __shared__ float xs[4][IND];
    const int b0 = blockIdx.x * 4;
    const int t  = threadIdx.x;

    if (t < 128) {
        ((float4*)xs)[t] = ((const float4*)(x + (size_t)b0 * IND))[t];
    }
    __syncthreads();

    const float4* w0 = (const float4*)(Win + (size_t)t * IND);
    const float4* w1 = (const float4*)(Win + (size_t)(t + 256) * IND);

    float acc[2][4] = {};
    for (int k4 = 0; k4 < IND / 4; ++k4) {
        float4 a0 = w0[k4];
        float4 a1 = w1[k4];
#pragma unroll
        for (int bb = 0; bb < 4; ++bb) {
            float4 hv = ((const float4*)xs[bb])[k4];
            acc[0][bb] += dot4(a0, hv);
            acc[1][bb] += dot4(a1, hv);
        }
    }
    const float bi0 = bin[t];
    const float bi1 = bin[t + 256];
#pragma unroll
    for (int bb = 0; bb < 4; ++bb) {
        h[(size_t)(b0 + bb) * H + t]       = silu_f(acc[0][bb] + bi0);
        h[(size_t)(b0 + bb) * H + t + 256] = silu_f(acc[1][bb] + bi1);
    }
}

// ---------------------------------------------------------------------------
// K2: Q/K/V = silu(h @ A^T + B)  three 512x512 GEMMs, K=512.
// grid (128, 2): x = 4-batch-row tile, y = which half of the 512 rows of A.
// Each thread computes 1 row of each of Aq/Ak/Av for 4 batch rows (12 accs).
// ---------------------------------------------------------------------------
__global__ __launch_bounds__(256) void k_qkv(const float* __restrict__ h,
                                             const float* __restrict__ Aq,
                                             const float* __restrict__ Bq,
                                             const float* __restrict__ Ak,
                                             const float* __restrict__ Bk,
                                             const float* __restrict__ Av,
                                             const float* __restrict__ Bv,
                                             float* __restrict__ qkv) {
    __shared__ float hs[4][H];   // 8 KB
    const int b0   = blockIdx.x * 4;
    const int half = blockIdx.y;
    const int t    = threadIdx.x;

    {
        const float4* src = (const float4*)(h + (size_t)b0 * H);
        float4*       dst = (float4*)hs;
        dst[t]       = src[t];
        dst[t + 256] = src[t + 256];
    }
    __syncthreads();

    const int r = half * 256 + t;
    const float4* aq = (const float4*)(Aq + (size_t)r * H);
    const float4* ak = (const float4*)(Ak + (size_t)r * H);
    const float4* av = (const float4*)(Av + (size_t)r * H);

    float acc[3][4] = {};
    for (int k4 = 0; k4 < H / 4; ++k4) {
        float4 q  = aq[k4];
        float4 kk = ak[k4];
        float4 v  = av[k4];
#pragma unroll
        for (int bb = 0; bb < 4; ++bb) {
            float4 hv = ((const float4*)hs[bb])[k4];
            acc[0][bb] += dot4(q,  hv);
            acc[1][bb] += dot4(kk, hv);
            acc[2][bb] += dot4(v,  hv);
        }
    }
    const float bq = Bq[r], bk = Bk[r], bv = Bv[r];
#pragma unroll
    for (int bb = 0; bb < 4; ++bb) {
        const size_t row = (size_t)(b0 + bb) * H + r;
        qkv[0 * (size_t)NB * H + row] = silu_f(acc[0][bb] + bq);
        qkv[1 * (size_t)NB * H + row] = silu_f(acc[1][bb] + bk);
        qkv[2 * (size_t)NB * H + row] = silu_f(acc[2][bb] + bv);
    }
}

// ---------------------------------------------------------------------------
// K3: ctx[b,i] = silu( sum_j softmax_j(Q[b,i]*K[b,j]) * V[b,j] )
// One block per batch row; 512 threads, thread i handles output i.
// Row max of s*K[:] is exactly s*maxK (s>=0) or s*minK (s<0) -- rounding
// is monotone so this matches jax's elementwise-max to the ulp.
// ---------------------------------------------------------------------------
__global__ __launch_bounds__(512) void k_attn(const float* __restrict__ qkv,
                                              float* __restrict__ ctx) {
    __shared__ float Ks[H];
    __shared__ float Vs[H];
    __shared__ float wmx[8], wmn[8];

    const int b = blockIdx.x;
    const int t = threadIdx.x;

    const float* Q = qkv + (size_t)b * H;
    const float* K = qkv + 1 * (size_t)NB * H + (size_t)b * H;
    const float* V = qkv + 2 * (size_t)NB * H + (size_t)b * H;

    const float kv = K[t];
    Ks[t] = kv;
    Vs[t] = V[t];

    // wave-level max/min reduce, then 8-way LDS combine
    float mx = kv, mn = kv;
#pragma unroll
    for (int o = 32; o > 0; o >>= 1) {
        mx = fmaxf(mx, __shfl_xor(mx, o, 64));
        mn = fminf(mn, __shfl_xor(mn, o, 64));
    }
    const int lane = t & 63, w = t >> 6;
    if (lane == 0) { wmx[w] = mx; wmn[w] = mn; }
    __syncthreads();

    float gmx = wmx[0], gmn = wmn[0];
#pragma unroll
    for (int i = 1; i < 8; ++i) {
        gmx = fmaxf(gmx, wmx[i]);
        gmn = fminf(gmn, wmn[i]);
    }

    const float s  = Q[t];
    const float m  = (s >= 0.0f) ? s * gmx : s * gmn;
    const float nm = -m;

    float den = 0.0f, num = 0.0f;
    const float4* K4p = (const float4*)Ks;
    const float4* V4p = (const float4*)Vs;
    for (int j4 = 0; j4 < H / 4; ++j4) {
        float4 kj = K4p[j4];
        float4 vj = V4p[j4];
        float e0 = __expf(fmaf(s, kj.x, nm));
        float e1 = __expf(fmaf(s, kj.y, nm));
        float e2 = __expf(fmaf(s, kj.z, nm));
        float e3 = __expf(fmaf(s, kj.w, nm));
        den += (e0 + e1) + (e2 + e3);
        num = fmaf(e0, vj.x, num);
        num = fmaf(e1, vj.y, num);
        num = fmaf(e2, vj.z, num);
        num = fmaf(e3, vj.w, num);
    }
    ctx[(size_t)b * H + t] = silu_f(num / den);
}

// ---------------------------------------------------------------------------
// K4: y = silu(ctx @ W_out^T + b_out); out[b] = q^T M q + mpp
// One block per batch row. 25 outputs x 8 K-partials = 200 active threads.
// ---------------------------------------------------------------------------
__global__ __launch_bounds__(256) void k_out(const float* __restrict__ ctx,
                                             const float* __restrict__ Wout,
                                             const float* __restrict__ bout,
                                             float* __restrict__ out) {
    __shared__ float cs[H];
    __shared__ float part[OUTD][8];
    __shared__ float yrow[OUTD];

    const int b = blockIdx.x;
    const int t = threadIdx.x;

    cs[t]       = ctx[(size_t)b * H + t];
    cs[t + 256] = ctx[(size_t)b * H + t + 256];
    __syncthreads();

    if (t < OUTD * 8) {
        const int o = t >> 3, p = t & 7;
        const float4* w = (const float4*)(Wout + (size_t)o * H + p * 64);
        const float4* c = (const float4*)(cs + p * 64);
        float a = 0.0f;
#pragma unroll
        for (int k = 0; k < 16; ++k) a += dot4(w[k], c[k]);
        part[o][p] = a;
    }
    __syncthreads();

    if (t < OUTD) {
        float a = bout[t];
#pragma unroll
        for (int p = 0; p < 8; ++p) a += part[t][p];
        yrow[t] = silu_f(a);
    }
    __syncthreads();

    if (t == 0) {
        float ms[5];
#pragma unroll
        for (int g = 0; g < 5; ++g) {
            float a = 0.0f;
#pragma unroll
            for (int k = 0; k < 5; ++k) {
                const float yv = yrow[g * 5 + k];
                a = fmaf(yv, yv, a);
            }
            ms[g] = a;
        }
        const float m11 = ms[0], m12 = ms[1], m21 = ms[2], m22 = ms[3], mpp = ms[4];
        const float q0 = yrow[0], q1 = yrow[1], q2 = yrow[2], q3 = yrow[3];
        const float quad = m11 * (q0 * q0 + q1 * q1)
                         + (m12 + m21) * (q0 * q2 + q1 * q3)
                         + m22 * (q2 * q2 + q3 * q3);
        out[b] = quad + mpp;
    }
}

// ---------------------------------------------------------------------------
extern "C" void kernel_launch(void* const* d_in, const int* in_sizes, int n_in,
                              void* d_out, int out_size, void* d_ws, size_t ws_size,
                              hipStream_t stream) {
    const float* x    = (const float*)d_in[0];
    // d_in[1] = na (int32, unused by the reference math)
    const float* Win  = (const float*)d_in[2];
    const float* bin  = (const float*)d_in[3];
    const float* Aq   = (const float*)d_in[4];
    const float* Bq   = (const float*)d_in[5];
    const float* Ak   = (const float*)d_in[6];
    const float* Bk   = (const float*)d_in[7];
    const float* Av   = (const float*)d_in[8];
    const float* Bv   = (const float*)d_in[9];
    const float* Wout = (const float*)d_in[10];
    const float* bout = (const float*)d_in[11];

    float* out = (float*)d_out;
    float* ws  = (float*)d_ws;

    float* h   = ws;                          // 512*512
    float* qkv = ws + (size_t)NB * H;         // 3 * 512*512
    float* ctx = ws + 4 * (size_t)NB * H;     // 512*512

    k_hin <<<dim3(NB / 4),    dim3(256), 0, stream>>>(x, Win, bin, h);
    k_qkv <<<dim3(NB / 4, 2), dim3(256), 0, stream>>>(h, Aq, Bq, Ak, Bk, Av, Bv, qkv);
    k_attn<<<dim3(NB),        dim3(512), 0, stream>>>(qkv, ctx);
    k_out <<<dim3(NB),        dim3(256), 0, stream>>>(ctx, Wout, bout, out);
}

// Round 7
// 145.756 us; speedup vs baseline: 1.1887x; 1.1887x over previous
//
#include <hip/hip_runtime.h>

#define NB   512   // batch
#define IND  128   // input dim
#define H    512   // hidden
#define OUTD 25    // out dim

__device__ __forceinline__ float silu_f(float v) {
    return v / (1.0f + __expf(-v));
}

__device__ __forceinline__ float dot4(float4 a, float4 b) {
    return fmaf(a.x, b.x, fmaf(a.y, b.y, fmaf(a.z, b.z, a.w * b.w)));
}

// ---------------------------------------------------------------------------
// K1: h = silu(x @ W_in^T + b_in)
// grid (256, 2) = 512 blocks, 256 threads. Block: 2 batch rows x 256 cols.
// x rows are block-uniform -> compiler scalarizes to s_load (no LDS needed).
// ---------------------------------------------------------------------------
__global__ __launch_bounds__(256) void k_hin(const float* __restrict__ x,
                                             const float* __restrict__ Win,
                                             const float* __restrict__ bin,
                                             float* __restrict__ h) {
    const int b0  = blockIdx.x * 2;
    const int col = blockIdx.y * 256 + threadIdx.x;

    const float4* w  = (const float4*)(Win + (size_t)col * IND);
    const float4* x0 = (const float4*)(x + (size_t)b0 * IND);
    const float4* x1 = (const float4*)(x + (size_t)(b0 + 1) * IND);

    float a0 = 0.0f, a1 = 0.0f;
#pragma unroll 8
    for (int k4 = 0; k4 < IND / 4; ++k4) {
        const float4 wv = w[k4];
        a0 += dot4(wv, x0[k4]);   // x0/x1 uniform -> s_load_dwordx4
        a1 += dot4(wv, x1[k4]);
    }
    const float bi = bin[col];
    h[(size_t)b0 * H + col]       = silu_f(a0 + bi);
    h[(size_t)(b0 + 1) * H + col] = silu_f(a1 + bi);
}

// ---------------------------------------------------------------------------
// K2: Q/K/V = silu(h @ A^T + B)
// grid (64, 4, 3) = 768 blocks (3/CU), 128 threads.
// Block: 8 batch rows x 128 weight rows x 1 matrix. Thread: 1 weight-row
// stream (per-lane float4 loads) x 8 uniform h rows (scalarized loads).
// ILP = 8 independent FMA chains per weight load; no LDS, no barriers.
// ---------------------------------------------------------------------------
__global__ __launch_bounds__(128) void k_qkv(const float* __restrict__ h,
                                             const float* __restrict__ Aq,
                                             const float* __restrict__ Bq,
                                             const float* __restrict__ Ak,
                                             const float* __restrict__ Bk,
                                             const float* __restrict__ Av,
                                             const float* __restrict__ Bv,
                                             float* __restrict__ qkv) {
    const int b0 = blockIdx.x * 8;
    const int r  = blockIdx.y * 128 + threadIdx.x;
    const int m  = blockIdx.z;

    const float* A  = (m == 0) ? Aq : (m == 1) ? Ak : Av;
    const float* Bb = (m == 0) ? Bq : (m == 1) ? Bk : Bv;

    const float4* w = (const float4*)(A + (size_t)r * H);

    float acc[8] = {};
#pragma unroll 2
    for (int k4 = 0; k4 < H / 4; ++k4) {
        const float4 wv = w[k4];
#pragma unroll
        for (int bb = 0; bb < 8; ++bb) {
            const float4 hv = *(const float4*)(h + (size_t)(b0 + bb) * H + k4 * 4);
            acc[bb] += dot4(wv, hv);   // hv uniform -> s_load_dwordx4
        }
    }
    const float bias = Bb[r];
#pragma unroll
    for (int bb = 0; bb < 8; ++bb) {
        qkv[(size_t)m * NB * H + (size_t)(b0 + bb) * H + r] = silu_f(acc[bb] + bias);
    }
}

// ---------------------------------------------------------------------------
// K3: ctx[b,i] = silu( sum_j softmax_j(Q[b,i]*K[b,j]) * V[b,j] )
// One block per batch row, 512 threads. K/V reads in the main loop are
// block-uniform -> scalarized; only the max/min reduce uses per-lane data.
// Row max of s*K[:] is exactly s*maxK (s>=0) or s*minK (s<0): rounding is
// monotone, so this matches the reference's elementwise max exactly.
// ---------------------------------------------------------------------------
__global__ __launch_bounds__(512) void k_attn(const float* __restrict__ qkv,
                                              float* __restrict__ ctx) {
    __shared__ float wmx[8], wmn[8];

    const int b = blockIdx.x;
    const int t = threadIdx.x;

    const float* Q = qkv + (size_t)b * H;
    const float* K = qkv + 1 * (size_t)NB * H + (size_t)b * H;
    const float* V = qkv + 2 * (size_t)NB * H + (size_t)b * H;

    // global max/min of K row: per-lane read + wave shuffle + 8-way combine
    const float kv = K[t];
    float mx = kv, mn = kv;
#pragma unroll
    for (int o = 32; o > 0; o >>= 1) {
        mx = fmaxf(mx, __shfl_xor(mx, o, 64));
        mn = fminf(mn, __shfl_xor(mn, o, 64));
    }
    const int lane = t & 63, w = t >> 6;
    if (lane == 0) { wmx[w] = mx; wmn[w] = mn; }
    __syncthreads();

    float gmx = wmx[0], gmn = wmn[0];
#pragma unroll
    for (int i = 1; i < 8; ++i) {
        gmx = fmaxf(gmx, wmx[i]);
        gmn = fminf(gmn, wmn[i]);
    }

    const float s  = Q[t];
    const float m  = (s >= 0.0f) ? s * gmx : s * gmn;
    const float nm = -m;

    float den = 0.0f, num = 0.0f;
    const float4* K4p = (const float4*)K;   // uniform addresses -> s_load
    const float4* V4p = (const float4*)V;
#pragma unroll 4
    for (int j4 = 0; j4 < H / 4; ++j4) {
        const float4 kj = K4p[j4];
        const float4 vj = V4p[j4];
        const float e0 = __expf(fmaf(s, kj.x, nm));
        const float e1 = __expf(fmaf(s, kj.y, nm));
        const float e2 = __expf(fmaf(s, kj.z, nm));
        const float e3 = __expf(fmaf(s, kj.w, nm));
        den += (e0 + e1) + (e2 + e3);
        num = fmaf(e0, vj.x, num);
        num = fmaf(e1, vj.y, num);
        num = fmaf(e2, vj.z, num);
        num = fmaf(e3, vj.w, num);
    }
    ctx[(size_t)b * H + t] = silu_f(num / den);
}

// ---------------------------------------------------------------------------
// K4: y = silu(ctx @ W_out^T + b_out); out[b] = q^T M q + mpp
// One block per batch row. 25 outputs x 8 K-partials = 200 active threads.
// ---------------------------------------------------------------------------
__global__ __launch_bounds__(256) void k_out(const float* __restrict__ ctx,
                                             const float* __restrict__ Wout,
                                             const float* __restrict__ bout,
                                             float* __restrict__ out) {
    __shared__ float cs[H];
    __shared__ float part[OUTD][8];
    __shared__ float yrow[OUTD];

    const int b = blockIdx.x;
    const int t = threadIdx.x;

    cs[t]       = ctx[(size_t)b * H + t];
    cs[t + 256] = ctx[(size_t)b * H + t + 256];
    __syncthreads();

    if (t < OUTD * 8) {
        const int o = t >> 3, p = t & 7;
        const float4* w = (const float4*)(Wout + (size_t)o * H + p * 64);
        const float4* c = (const float4*)(cs + p * 64);
        float a = 0.0f;
#pragma unroll
        for (int k = 0; k < 16; ++k) a += dot4(w[k], c[k]);
        part[o][p] = a;
    }
    __syncthreads();

    if (t < OUTD) {
        float a = bout[t];
#pragma unroll
        for (int p = 0; p < 8; ++p) a += part[t][p];
        yrow[t] = silu_f(a);
    }
    __syncthreads();

    if (t == 0) {
        float ms[5];
#pragma unroll
        for (int g = 0; g < 5; ++g) {
            float a = 0.0f;
#pragma unroll
            for (int k = 0; k < 5; ++k) {
                const float yv = yrow[g * 5 + k];
                a = fmaf(yv, yv, a);
            }
            ms[g] = a;
        }
        const float m11 = ms[0], m12 = ms[1], m21 = ms[2], m22 = ms[3], mpp = ms[4];
        const float q0 = yrow[0], q1 = yrow[1], q2 = yrow[2], q3 = yrow[3];
        const float quad = m11 * (q0 * q0 + q1 * q1)
                         + (m12 + m21) * (q0 * q2 + q1 * q3)
                         + m22 * (q2 * q2 + q3 * q3);
        out[b] = quad + mpp;
    }
}

// ---------------------------------------------------------------------------
extern "C" void kernel_launch(void* const* d_in, const int* in_sizes, int n_in,
                              void* d_out, int out_size, void* d_ws, size_t ws_size,
                              hipStream_t stream) {
    const float* x    = (const float*)d_in[0];
    // d_in[1] = na (int32, unused by the reference math)
    const float* Win  = (const float*)d_in[2];
    const float* bin  = (const float*)d_in[3];
    const float* Aq   = (const float*)d_in[4];
    const float* Bq   = (const float*)d_in[5];
    const float* Ak   = (const float*)d_in[6];
    const float* Bk   = (const float*)d_in[7];
    const float* Av   = (const float*)d_in[8];
    const float* Bv   = (const float*)d_in[9];
    const float* Wout = (const float*)d_in[10];
    const float* bout = (const float*)d_in[11];

    float* out = (float*)d_out;
    float* ws  = (float*)d_ws;

    float* h   = ws;                          // 512*512
    float* qkv = ws + (size_t)NB * H;         // 3 * 512*512
    float* ctx = ws + 4 * (size_t)NB * H;     // 512*512

    k_hin <<<dim3(NB / 2, 2),    dim3(256), 0, stream>>>(x, Win, bin, h);
    k_qkv <<<dim3(NB / 8, 4, 3), dim3(128), 0, stream>>>(h, Aq, Bq, Ak, Bk, Av, Bv, qkv);
    k_attn<<<dim3(NB),           dim3(512), 0, stream>>>(qkv, ctx);
    k_out <<<dim3(NB),           dim3(256), 0, stream>>>(ctx, Wout, bout, out);
}